// Round 1
// baseline (671.128 us; speedup 1.0000x reference)
//
#include <hip/hip_runtime.h>
#include <hip/hip_fp16.h>
#include <cstdint>
#include <math.h>

#define INP  3072
#define HID  1024
#define OUTD 768
#define BSZ  8192

typedef _Float16 f16;
typedef _Float16 f16x8 __attribute__((ext_vector_type(8)));
typedef float    f32x4 __attribute__((ext_vector_type(4)));

// ---------------- workspace layout (bytes) ----------------
// XH region (50.3MB) is reused after GEMM1 for PN/YN/partials.
static constexpr size_t OFF_XH   = 0;
static constexpr size_t OFF_PN   = 0;
static constexpr size_t OFF_YN   = OFF_PN   + (size_t)BSZ*OUTD*2;   // 12582912
static constexpr size_t OFF_PSUM = OFF_YN   + (size_t)BSZ*OUTD*2;   // 25165824
static constexpr size_t OFF_PMAX = OFF_PSUM + (size_t)BSZ*64*4;
static constexpr size_t OFF_PIDX = OFF_PMAX + (size_t)BSZ*64*4;     // ends 31457280 <= 50331648
static constexpr size_t OFF_HB   = OFF_XH   + (size_t)BSZ*INP*2;    // 50331648
static constexpr size_t OFF_TT   = OFF_HB   + (size_t)BSZ*HID*2;    // 67108864 (T f16 / PRE2 f32 share)
static constexpr size_t OFF_H    = OFF_TT   + (size_t)BSZ*OUTD*4;   // 92274688
static constexpr size_t OFF_W1T  = OFF_H    + (size_t)BSZ*HID*4;    // 125829120
static constexpr size_t OFF_WAT  = OFF_W1T  + (size_t)INP*HID*2;
static constexpr size_t OFF_WBT  = OFF_WAT  + (size_t)HID*HID*2;
static constexpr size_t OFF_W2T  = OFF_WBT  + (size_t)HID*HID*2;
static constexpr size_t OFF_DIAG = OFF_W2T  + (size_t)HID*OUTD*2;
static constexpr size_t OFF_ACC  = OFF_DIAG + (size_t)BSZ*4;        // 4 floats

// global_load_lds, width 16: LDS dest = wave-uniform base + lane*16
#define GL2LDS(gp, lp) __builtin_amdgcn_global_load_lds( \
    (__attribute__((address_space(1))) void*)(uintptr_t)(gp), \
    (__attribute__((address_space(3))) void*)(unsigned)(uintptr_t)(lp), 16, 0, 0)

// ---------------- small helpers ----------------
__device__ __forceinline__ float blk_sum256(float v, float* sm) {
  #pragma unroll
  for (int d = 1; d < 64; d <<= 1) v += __shfl_xor(v, d, 64);
  int tid = threadIdx.x;
  __syncthreads();
  if ((tid & 63) == 0) sm[tid >> 6] = v;
  __syncthreads();
  return sm[0] + sm[1] + sm[2] + sm[3];
}

// ---------------- LN1: inp[8192,3072] -> xh f16 ----------------
__global__ __launch_bounds__(256) void ln1_kernel(const float* __restrict__ inp,
    const float* __restrict__ g, const float* __restrict__ b, f16* __restrict__ xh) {
  __shared__ float sm[4];
  const int row = blockIdx.x, tid = threadIdx.x;
  const float* x = inp + (size_t)row * INP;
  float v[12]; float s = 0.f;
  #pragma unroll
  for (int i = 0; i < 12; i++) { v[i] = x[tid + i*256]; s += v[i]; }
  const float mean = blk_sum256(s, sm) * (1.f/INP);
  float s2 = 0.f;
  #pragma unroll
  for (int i = 0; i < 12; i++) { float d = v[i]-mean; s2 += d*d; }
  const float rstd = rsqrtf(blk_sum256(s2, sm) * (1.f/INP) + 1e-5f);
  f16* o = xh + (size_t)row * INP;
  #pragma unroll
  for (int i = 0; i < 12; i++) {
    int c = tid + i*256;
    o[c] = (f16)((v[i]-mean)*rstd*g[c] + b[c]);
  }
}

// ---------------- weight transpose+cast: W[K,N] f32 -> Wt[N,K] f16 ----------------
__global__ __launch_bounds__(256) void transpose_cast(const float* __restrict__ W,
    f16* __restrict__ Wt, int K, int N) {
  __shared__ float t[32][33];
  const int n0 = blockIdx.x*32, k0 = blockIdx.y*32;
  const int tx = threadIdx.x & 31, ty = threadIdx.x >> 5;  // 32 x 8
  #pragma unroll
  for (int i = 0; i < 32; i += 8) t[ty+i][tx] = W[(size_t)(k0+ty+i)*N + n0+tx];
  __syncthreads();
  #pragma unroll
  for (int i = 0; i < 32; i += 8) Wt[(size_t)(n0+ty+i)*K + k0+tx] = (f16)t[tx][ty+i];
}

// ---------------- LN2 + normalize: pre2[8192,768] -> d_out rows + pn f16 ----------------
__global__ __launch_bounds__(256) void ln2_kernel(const float* __restrict__ pre,
    const float* __restrict__ g, const float* __restrict__ b,
    float* __restrict__ outY, f16* __restrict__ pn) {
  __shared__ float sm[4];
  const int row = blockIdx.x, tid = threadIdx.x;
  const float* x = pre + (size_t)row * OUTD;
  float v[3]; float s = 0.f;
  #pragma unroll
  for (int i = 0; i < 3; i++) { v[i] = x[tid + i*256]; s += v[i]; }
  const float mean = blk_sum256(s, sm) * (1.f/OUTD);
  float s2 = 0.f;
  #pragma unroll
  for (int i = 0; i < 3; i++) { float d = v[i]-mean; s2 += d*d; }
  const float rstd = rsqrtf(blk_sum256(s2, sm) * (1.f/OUTD) + 1e-5f);
  float z[3]; float n2 = 0.f;
  #pragma unroll
  for (int i = 0; i < 3; i++) { int c = tid + i*256; z[i] = (v[i]-mean)*rstd*g[c] + b[c]; n2 += z[i]*z[i]; }
  const float rn = rsqrtf(blk_sum256(n2, sm));
  float* oy = outY + (size_t)row * OUTD;
  f16*   op = pn   + (size_t)row * OUTD;
  #pragma unroll
  for (int i = 0; i < 3; i++) { int c = tid + i*256; oy[c] = z[i]; op[c] = (f16)(z[i]*rn); }
}

// ---------------- yn: y[8192,768] -> unit rows f16 ----------------
__global__ __launch_bounds__(256) void yn_kernel(const float* __restrict__ y, f16* __restrict__ yn) {
  __shared__ float sm[4];
  const int row = blockIdx.x, tid = threadIdx.x;
  const float* x = y + (size_t)row * OUTD;
  float v[3]; float n2 = 0.f;
  #pragma unroll
  for (int i = 0; i < 3; i++) { v[i] = x[tid + i*256]; n2 += v[i]*v[i]; }
  const float rn = rsqrtf(blk_sum256(n2, sm));
  f16* o = yn + (size_t)row * OUTD;
  #pragma unroll
  for (int i = 0; i < 3; i++) { int c = tid + i*256; o[c] = (f16)(v[i]*rn); }
}

// ---------------- m97-style GEMM, B^T input ([N][K], K-contiguous) ----------------
#define EPI_H   0  // C+=b1; write H f32 + HB f16
#define EPI_T   1  // C+=ba; relu; write T f16
#define EPI_RES 2  // C+=bb; relu; +=Hin; write H f32 + HB f16 (in place)
#define EPI_P   3  // C+=b2; write PRE2 f32
#define EPI_S   4  // cosine-sim tile: exp/max/argmax row reduction -> partials

template<int EPI>
__global__ __launch_bounds__(256) void gemm_bt(
    const f16* __restrict__ A, const f16* __restrict__ B, int K, int N,
    const float* __restrict__ bias, float* __restrict__ Cf, f16* __restrict__ Ch,
    const float* __restrict__ Hin,
    float* __restrict__ partsum, float* __restrict__ partmax,
    int* __restrict__ partidx, float* __restrict__ diagv)
{
  __shared__ alignas(16) f16 lA[128*32];
  __shared__ alignas(16) f16 lB[128*32];
  const int tid  = threadIdx.x;
  const int wave = tid >> 6, lane = tid & 63;
  const int m0 = blockIdx.x * 128, n0 = blockIdx.y * 128;
  const int srow  = tid >> 2;         // 0..63 staging row
  const int skcol = (tid & 3) * 8;    // halves
  const f16* gA = A + (size_t)(m0 + srow) * K + skcol;
  const f16* gB = B + (size_t)(n0 + srow) * K + skcol;
  f16* lAw = lA + wave*16*32;
  f16* lBw = lB + wave*16*32;
  const int wm = wave & 1, wn = wave >> 1;   // 2x2 waves of 64x64
  const int fm = lane & 15;
  const int g4 = lane >> 4;
  const int fk = g4 * 8;

  f32x4 acc[4][4];
  #pragma unroll
  for (int i = 0; i < 4; i++)
    #pragma unroll
    for (int j = 0; j < 4; j++) acc[i][j] = (f32x4){0.f,0.f,0.f,0.f};

  for (int k0 = 0; k0 < K; k0 += 32) {
    GL2LDS(gA + k0,                lAw);
    GL2LDS(gA + (size_t)64*K + k0, lAw + 64*32);
    GL2LDS(gB + k0,                lBw);
    GL2LDS(gB + (size_t)64*K + k0, lBw + 64*32);
    __syncthreads();
    f16x8 af[4], bf[4];
    #pragma unroll
    for (int i = 0; i < 4; i++) af[i] = *(const f16x8*)&lA[(wm*64 + i*16 + fm)*32 + fk];
    #pragma unroll
    for (int j = 0; j < 4; j++) bf[j] = *(const f16x8*)&lB[(wn*64 + j*16 + fm)*32 + fk];
    #pragma unroll
    for (int i = 0; i < 4; i++)
      #pragma unroll
      for (int j = 0; j < 4; j++)
        acc[i][j] = __builtin_amdgcn_mfma_f32_16x16x32_f16(af[i], bf[j], acc[i][j], 0, 0, 0);
    __syncthreads();
  }

  // epilogue. C/D layout: col = lane&15, row = (lane>>4)*4 + reg
  if constexpr (EPI != EPI_S) {
    const int colb = n0 + wn*64;
    const int rowb = m0 + wm*64;
    #pragma unroll
    for (int i = 0; i < 4; i++) {
      #pragma unroll
      for (int j = 0; j < 4; j++) {
        const int col = colb + j*16 + fm;
        const float bs = bias[col];
        #pragma unroll
        for (int r = 0; r < 4; r++) {
          const int row = rowb + i*16 + g4*4 + r;
          float v = acc[i][j][r] + bs;
          const size_t idx = (size_t)row * N + col;
          if constexpr (EPI == EPI_H)        { Cf[idx] = v; Ch[idx] = (f16)v; }
          else if constexpr (EPI == EPI_T)   { v = fmaxf(v, 0.f); Ch[idx] = (f16)v; }
          else if constexpr (EPI == EPI_RES) { v = fmaxf(v, 0.f); v += Hin[idx]; Cf[idx] = v; Ch[idx] = (f16)v; }
          else                               { Cf[idx] = v; }
        }
      }
    }
  } else {
    __shared__ float redS[2][128], redM[2][128];
    __shared__ int   redI[2][128];
    const int bn = blockIdx.y;
    #pragma unroll
    for (int i = 0; i < 4; i++) {
      #pragma unroll
      for (int r = 0; r < 4; r++) {
        const int lrow = wm*64 + i*16 + g4*4 + r;
        const int grow = m0 + lrow;
        float s = 0.f, mx = -1e30f; int mi = 0x7fffffff;
        #pragma unroll
        for (int j = 0; j < 4; j++) {
          const int gcol = n0 + wn*64 + j*16 + fm;
          const float v = acc[i][j][r];
          if (grow == gcol) diagv[grow] = v;   // S_ii for -sum(pn*yn)
          s += __expf(v);                       // |S|<=~1: no max-shift needed
          if (v > mx) { mx = v; mi = gcol; }
        }
        #pragma unroll
        for (int d = 1; d < 16; d <<= 1) {
          s += __shfl_xor(s, d, 64);
          const float om = __shfl_xor(mx, d, 64);
          const int   oi = __shfl_xor(mi, d, 64);
          if (om > mx || (om == mx && oi < mi)) { mx = om; mi = oi; }
        }
        if (fm == 0) { redS[wn][lrow] = s; redM[wn][lrow] = mx; redI[wn][lrow] = mi; }
      }
    }
    __syncthreads();
    if (tid < 128) {
      const float sa = redS[0][tid] + redS[1][tid];
      const float ma = redM[0][tid], mb = redM[1][tid];
      const int   ia = redI[0][tid], ib = redI[1][tid];
      float mx; int mi;
      if (ma > mb || (ma == mb && ia < ib)) { mx = ma; mi = ia; } else { mx = mb; mi = ib; }
      const size_t p = (size_t)bn * BSZ + m0 + tid;   // [colblock][row] for coalesced reduce
      partsum[p] = sa; partmax[p] = mx; partidx[p] = mi;
    }
  }
}

// ---------------- per-row final reduce ----------------
__global__ __launch_bounds__(256) void reduce_rows(const float* __restrict__ partsum,
    const float* __restrict__ partmax, const int* __restrict__ partidx,
    const float* __restrict__ diagv, float* __restrict__ accum) {
  __shared__ float sm[4];
  const int row = blockIdx.x*256 + threadIdx.x;
  float s = 0.f, mx = -1e30f; int mi = 0x7fffffff;
  for (int i = 0; i < 64; i++) {
    s += partsum[(size_t)i*BSZ + row];
    const float m = partmax[(size_t)i*BSZ + row];
    const int  ii = partidx[(size_t)i*BSZ + row];
    if (m > mx || (m == mx && ii < mi)) { mx = m; mi = ii; }
  }
  const float lse  = logf(s);
  const float corr = (mi == row) ? 1.f : 0.f;
  const float dg   = diagv[row];
  const float lse_s = blk_sum256(lse, sm);
  const float dg_s  = blk_sum256(dg, sm);
  const float c_s   = blk_sum256(corr, sm);
  if (threadIdx.x == 0) {
    atomicAdd(&accum[0], lse_s);
    atomicAdd(&accum[1], dg_s);
    atomicAdd(&accum[2], c_s);
  }
}

__global__ void finalize_kernel(const float* __restrict__ accum, float* __restrict__ out) {
  out[0] = accum[0] - accum[1];        // loss = sum(lse) - sum(diag)
  out[1] = accum[2] * (1.f / BSZ);     // acc
}

// ---------------- launch ----------------
extern "C" void kernel_launch(void* const* d_in, const int* in_sizes, int n_in,
                              void* d_out, int out_size, void* d_ws, size_t ws_size,
                              hipStream_t stream) {
  const float* inp  = (const float*)d_in[0];
  const float* y    = (const float*)d_in[1];
  const float* ln1g = (const float*)d_in[2];
  const float* ln1b = (const float*)d_in[3];
  const float* W1   = (const float*)d_in[4];
  const float* b1   = (const float*)d_in[5];
  const float* Wa   = (const float*)d_in[6];
  const float* ba   = (const float*)d_in[7];
  const float* Wb   = (const float*)d_in[8];
  const float* bb   = (const float*)d_in[9];
  const float* W2   = (const float*)d_in[10];
  const float* b2   = (const float*)d_in[11];
  const float* ln2g = (const float*)d_in[12];
  const float* ln2b = (const float*)d_in[13];
  float* out = (float*)d_out;

  char* ws = (char*)d_ws;
  f16*   XH   = (f16*)  (ws + OFF_XH);
  f16*   PN   = (f16*)  (ws + OFF_PN);
  f16*   YN   = (f16*)  (ws + OFF_YN);
  float* PSUM = (float*)(ws + OFF_PSUM);
  float* PMAX = (float*)(ws + OFF_PMAX);
  int*   PIDX = (int*)  (ws + OFF_PIDX);
  f16*   HB   = (f16*)  (ws + OFF_HB);
  f16*   T    = (f16*)  (ws + OFF_TT);
  float* PRE2 = (float*)(ws + OFF_TT);
  float* H    = (float*)(ws + OFF_H);
  f16*   W1T  = (f16*)  (ws + OFF_W1T);
  f16*   WAT  = (f16*)  (ws + OFF_WAT);
  f16*   WBT  = (f16*)  (ws + OFF_WBT);
  f16*   W2T  = (f16*)  (ws + OFF_W2T);
  float* DIAG = (float*)(ws + OFF_DIAG);
  float* ACC  = (float*)(ws + OFF_ACC);

  // weight prep (every call: weights restored each launch)
  transpose_cast<<<dim3(HID/32,  INP/32), 256, 0, stream>>>(W1, W1T, INP, HID);
  transpose_cast<<<dim3(HID/32,  HID/32), 256, 0, stream>>>(Wa, WAT, HID, HID);
  transpose_cast<<<dim3(HID/32,  HID/32), 256, 0, stream>>>(Wb, WBT, HID, HID);
  transpose_cast<<<dim3(OUTD/32, HID/32), 256, 0, stream>>>(W2, W2T, HID, OUTD);

  ln1_kernel<<<BSZ, 256, 0, stream>>>(inp, ln1g, ln1b, XH);

  // h = LN(inp) @ W1 + b1
  gemm_bt<EPI_H><<<dim3(BSZ/128, HID/128), 256, 0, stream>>>(
      XH, W1T, INP, HID, b1, H, HB, nullptr, nullptr, nullptr, nullptr, nullptr);

  // two residual blocks (shared weights)
  for (int it = 0; it < 2; it++) {
    gemm_bt<EPI_T><<<dim3(BSZ/128, HID/128), 256, 0, stream>>>(
        HB, WAT, HID, HID, ba, nullptr, T, nullptr, nullptr, nullptr, nullptr, nullptr);
    gemm_bt<EPI_RES><<<dim3(BSZ/128, HID/128), 256, 0, stream>>>(
        T, WBT, HID, HID, bb, H, HB, H, nullptr, nullptr, nullptr, nullptr);
  }

  // pre2 = h @ W2 + b2
  gemm_bt<EPI_P><<<dim3(BSZ/128, OUTD/128), 256, 0, stream>>>(
      HB, W2T, HID, OUTD, b2, PRE2, nullptr, nullptr, nullptr, nullptr, nullptr, nullptr);

  // pred_y (-> d_out) + pn, yn
  ln2_kernel<<<BSZ, 256, 0, stream>>>(PRE2, ln2g, ln2b, out, PN);
  yn_kernel<<<BSZ, 256, 0, stream>>>(y, YN);

  hipMemsetAsync(ACC, 0, 4*sizeof(float), stream);

  // S = pn @ yn^T with fused exp-sum / max / argmax / diag extraction
  gemm_bt<EPI_S><<<dim3(BSZ/128, BSZ/128), 256, 0, stream>>>(
      PN, YN, OUTD, BSZ, nullptr, nullptr, nullptr, nullptr, PSUM, PMAX, PIDX, DIAG);

  reduce_rows<<<BSZ/256, 256, 0, stream>>>(PSUM, PMAX, PIDX, DIAG, ACC);
  finalize_kernel<<<1, 1, 0, stream>>>(ACC, out + (size_t)BSZ*OUTD);
}

// Round 2
// 588.680 us; speedup vs baseline: 1.1401x; 1.1401x over previous
//
#include <hip/hip_runtime.h>
#include <hip/hip_fp16.h>
#include <cstdint>
#include <math.h>

#define INP  3072
#define HID  1024
#define OUTD 768
#define BSZ  8192

typedef _Float16 f16;
typedef _Float16 f16x8 __attribute__((ext_vector_type(8)));
typedef float    f32x4 __attribute__((ext_vector_type(4)));

static constexpr float LOG2E = 1.44269504088896340736f;
static constexpr float LN2   = 0.69314718055994530942f;

// ---------------- workspace layout (bytes) ----------------
static constexpr size_t OFF_XH   = 0;
static constexpr size_t OFF_PN   = 0;
static constexpr size_t OFF_YN   = OFF_PN   + (size_t)BSZ*OUTD*2;
static constexpr size_t OFF_PSUM = OFF_YN   + (size_t)BSZ*OUTD*2;
static constexpr size_t OFF_PMAX = OFF_PSUM + (size_t)BSZ*64*4;
static constexpr size_t OFF_HB   = OFF_XH   + (size_t)BSZ*INP*2;
static constexpr size_t OFF_TT   = OFF_HB   + (size_t)BSZ*HID*2;
static constexpr size_t OFF_H    = OFF_TT   + (size_t)BSZ*OUTD*4;
static constexpr size_t OFF_W1T  = OFF_H    + (size_t)BSZ*HID*4;
static constexpr size_t OFF_WAT  = OFF_W1T  + (size_t)INP*HID*2;
static constexpr size_t OFF_WBT  = OFF_WAT  + (size_t)HID*HID*2;
static constexpr size_t OFF_W2T  = OFF_WBT  + (size_t)HID*HID*2;
static constexpr size_t OFF_DIAG = OFF_W2T  + (size_t)HID*OUTD*2;
static constexpr size_t OFF_ACC  = OFF_DIAG + (size_t)BSZ*4;

#define GL2LDS(gp, lp) __builtin_amdgcn_global_load_lds( \
    (__attribute__((address_space(1))) void*)(uintptr_t)(gp), \
    (__attribute__((address_space(3))) void*)(unsigned)(uintptr_t)(lp), 16, 0, 0)

__device__ __forceinline__ float blk_sum256(float v, float* sm) {
  #pragma unroll
  for (int d = 1; d < 64; d <<= 1) v += __shfl_xor(v, d, 64);
  int tid = threadIdx.x;
  __syncthreads();
  if ((tid & 63) == 0) sm[tid >> 6] = v;
  __syncthreads();
  return sm[0] + sm[1] + sm[2] + sm[3];
}

// ---------------- LN1 ----------------
__global__ __launch_bounds__(256) void ln1_kernel(const float* __restrict__ inp,
    const float* __restrict__ g, const float* __restrict__ b, f16* __restrict__ xh) {
  __shared__ float sm[4];
  const int row = blockIdx.x, tid = threadIdx.x;
  const float* x = inp + (size_t)row * INP;
  float v[12]; float s = 0.f;
  #pragma unroll
  for (int i = 0; i < 12; i++) { v[i] = x[tid + i*256]; s += v[i]; }
  const float mean = blk_sum256(s, sm) * (1.f/INP);
  float s2 = 0.f;
  #pragma unroll
  for (int i = 0; i < 12; i++) { float d = v[i]-mean; s2 += d*d; }
  const float rstd = rsqrtf(blk_sum256(s2, sm) * (1.f/INP) + 1e-5f);
  f16* o = xh + (size_t)row * INP;
  #pragma unroll
  for (int i = 0; i < 12; i++) {
    int c = tid + i*256;
    o[c] = (f16)((v[i]-mean)*rstd*g[c] + b[c]);
  }
}

// ---------------- weight transpose+cast ----------------
__global__ __launch_bounds__(256) void transpose_cast(const float* __restrict__ W,
    f16* __restrict__ Wt, int K, int N) {
  __shared__ float t[32][33];
  const int n0 = blockIdx.x*32, k0 = blockIdx.y*32;
  const int tx = threadIdx.x & 31, ty = threadIdx.x >> 5;
  #pragma unroll
  for (int i = 0; i < 32; i += 8) t[ty+i][tx] = W[(size_t)(k0+ty+i)*N + n0+tx];
  __syncthreads();
  #pragma unroll
  for (int i = 0; i < 32; i += 8) Wt[(size_t)(n0+ty+i)*K + k0+tx] = (f16)t[tx][ty+i];
}

// ---------------- LN2 + normalize (pn pre-scaled by log2e) ----------------
__global__ __launch_bounds__(256) void ln2_kernel(const float* __restrict__ pre,
    const float* __restrict__ g, const float* __restrict__ b,
    float* __restrict__ outY, f16* __restrict__ pn) {
  __shared__ float sm[4];
  const int row = blockIdx.x, tid = threadIdx.x;
  const float* x = pre + (size_t)row * OUTD;
  float v[3]; float s = 0.f;
  #pragma unroll
  for (int i = 0; i < 3; i++) { v[i] = x[tid + i*256]; s += v[i]; }
  const float mean = blk_sum256(s, sm) * (1.f/OUTD);
  float s2 = 0.f;
  #pragma unroll
  for (int i = 0; i < 3; i++) { float d = v[i]-mean; s2 += d*d; }
  const float rstd = rsqrtf(blk_sum256(s2, sm) * (1.f/OUTD) + 1e-5f);
  float z[3]; float n2 = 0.f;
  #pragma unroll
  for (int i = 0; i < 3; i++) { int c = tid + i*256; z[i] = (v[i]-mean)*rstd*g[c] + b[c]; n2 += z[i]*z[i]; }
  const float rn = rsqrtf(blk_sum256(n2, sm)) * LOG2E;   // pre-scale for exp2
  float* oy = outY + (size_t)row * OUTD;
  f16*   op = pn   + (size_t)row * OUTD;
  #pragma unroll
  for (int i = 0; i < 3; i++) { int c = tid + i*256; oy[c] = z[i]; op[c] = (f16)(z[i]*rn); }
}

// ---------------- yn ----------------
__global__ __launch_bounds__(256) void yn_kernel(const float* __restrict__ y, f16* __restrict__ yn) {
  __shared__ float sm[4];
  const int row = blockIdx.x, tid = threadIdx.x;
  const float* x = y + (size_t)row * OUTD;
  float v[3]; float n2 = 0.f;
  #pragma unroll
  for (int i = 0; i < 3; i++) { v[i] = x[tid + i*256]; n2 += v[i]*v[i]; }
  const float rn = rsqrtf(blk_sum256(n2, sm));
  f16* o = yn + (size_t)row * OUTD;
  #pragma unroll
  for (int i = 0; i < 3; i++) { int c = tid + i*256; o[c] = (f16)(v[i]*rn); }
}

// ---------------- GEMM: XOR-swizzled LDS, double-buffered prefetch ----------------
#define EPI_H   0
#define EPI_T   1
#define EPI_RES 2
#define EPI_P   3
#define EPI_S   4

template<int EPI>
__global__ __launch_bounds__(256) void gemm_bt(
    const f16* __restrict__ A, const f16* __restrict__ B, int K, int N,
    const float* __restrict__ bias, float* __restrict__ Cf, f16* __restrict__ Ch,
    const float* __restrict__ Hin,
    float* __restrict__ partsum, float* __restrict__ partmax, float* __restrict__ diagv)
{
  __shared__ alignas(16) f16 lA[2][128*32];
  __shared__ alignas(16) f16 lB[2][128*32];
  const int tid  = threadIdx.x;
  const int wave = tid >> 6, lane = tid & 63;
  const int m0 = blockIdx.x * 128, n0 = blockIdx.y * 128;
  const int srow  = tid >> 2;
  const int skc   = tid & 3;
  // XOR swizzle: LDS chunk (row, c) holds global chunk c ^ ((row>>1)&3).
  // global_load_lds fixes LDS dest = base + lane*16, so the swizzle is applied
  // on the GLOBAL address side here, and on the read index in the K-loop.
  const int skc_sw = skc ^ ((srow >> 1) & 3);
  const f16* gA = A + (size_t)(m0 + srow) * K + skc_sw*8;
  const f16* gB = B + (size_t)(n0 + srow) * K + skc_sw*8;
  const int wm = wave & 1, wn = wave >> 1;
  const int fm = lane & 15;
  const int g4 = lane >> 4;
  const int ks = (fm >> 1) & 3;        // read-side swizzle (row bits 1-2 == fm bits 1-2)
  const int ck = ((g4 ^ ks) * 8);      // swizzled k-chunk offset (elements)

  f32x4 acc[4][4];
  #pragma unroll
  for (int i = 0; i < 4; i++)
    #pragma unroll
    for (int j = 0; j < 4; j++) acc[i][j] = (f32x4){0.f,0.f,0.f,0.f};

  const int iters = K >> 5;
  auto stage = [&](int buf, int k0) {
    f16* lAw = &lA[buf][wave*16*32];
    f16* lBw = &lB[buf][wave*16*32];
    GL2LDS(gA + k0,                lAw);
    GL2LDS(gA + (size_t)64*K + k0, lAw + 64*32);
    GL2LDS(gB + k0,                lBw);
    GL2LDS(gB + (size_t)64*K + k0, lBw + 64*32);
  };

  stage(0, 0);
  __syncthreads();
  for (int it = 0; it < iters; ++it) {
    const int cur = it & 1;
    if (it + 1 < iters) stage(cur ^ 1, (it + 1) << 5);   // prefetch next tile
    f16x8 af[4], bf[4];
    #pragma unroll
    for (int i = 0; i < 4; i++) af[i] = *(const f16x8*)&lA[cur][(wm*64 + i*16 + fm)*32 + ck];
    #pragma unroll
    for (int j = 0; j < 4; j++) bf[j] = *(const f16x8*)&lB[cur][(wn*64 + j*16 + fm)*32 + ck];
    #pragma unroll
    for (int i = 0; i < 4; i++)
      #pragma unroll
      for (int j = 0; j < 4; j++)
        acc[i][j] = __builtin_amdgcn_mfma_f32_16x16x32_f16(af[i], bf[j], acc[i][j], 0, 0, 0);
    __syncthreads();
  }

  // epilogue. C/D layout: col = lane&15, row = (lane>>4)*4 + reg
  if constexpr (EPI != EPI_S) {
    const int colb = n0 + wn*64;
    const int rowb = m0 + wm*64;
    #pragma unroll
    for (int i = 0; i < 4; i++) {
      #pragma unroll
      for (int j = 0; j < 4; j++) {
        const int col = colb + j*16 + fm;
        const float bs = bias[col];
        #pragma unroll
        for (int r = 0; r < 4; r++) {
          const int row = rowb + i*16 + g4*4 + r;
          float v = acc[i][j][r] + bs;
          const size_t idx = (size_t)row * N + col;
          if constexpr (EPI == EPI_H)        { Cf[idx] = v; Ch[idx] = (f16)v; }
          else if constexpr (EPI == EPI_T)   { v = fmaxf(v, 0.f); Ch[idx] = (f16)v; }
          else if constexpr (EPI == EPI_RES) { v = fmaxf(v, 0.f); v += Hin[idx]; Cf[idx] = v; Ch[idx] = (f16)v; }
          else                               { Cf[idx] = v; }
        }
      }
    }
  } else {
    __shared__ float redS[2][128], redM[2][128];
    const int bn = blockIdx.y;
    if (m0 == n0) {               // uniform branch: only 64 of 4096 blocks
      #pragma unroll
      for (int i = 0; i < 4; i++)
        #pragma unroll
        for (int j = 0; j < 4; j++) {
          const int col = n0 + wn*64 + j*16 + fm;
          #pragma unroll
          for (int r = 0; r < 4; r++) {
            const int row = m0 + wm*64 + i*16 + g4*4 + r;
            if (row == col) diagv[row] = acc[i][j][r];   // scaled S_ii
          }
        }
    }
    #pragma unroll
    for (int i = 0; i < 4; i++) {
      #pragma unroll
      for (int r = 0; r < 4; r++) {
        const float a0 = acc[i][0][r], a1 = acc[i][1][r];
        const float a2 = acc[i][2][r], a3 = acc[i][3][r];
        float s  = exp2f(a0) + exp2f(a1) + exp2f(a2) + exp2f(a3);  // acc pre-scaled by log2e
        float mx = fmaxf(fmaxf(a0, a1), fmaxf(a2, a3));            // no index: corr test uses diag vs rowmax
        #pragma unroll
        for (int d = 1; d < 16; d <<= 1) {
          s  += __shfl_xor(s, d, 64);
          mx  = fmaxf(mx, __shfl_xor(mx, d, 64));
        }
        if (fm == 0) { const int lrow = wm*64 + i*16 + g4*4 + r; redS[wn][lrow] = s; redM[wn][lrow] = mx; }
      }
    }
    __syncthreads();
    if (tid < 128) {
      const float sa = redS[0][tid] + redS[1][tid];
      const float ma = fmaxf(redM[0][tid], redM[1][tid]);
      const size_t p = (size_t)bn * BSZ + m0 + tid;
      partsum[p] = sa; partmax[p] = ma;
    }
  }
}

// ---------------- per-row final reduce ----------------
__global__ __launch_bounds__(256) void reduce_rows(const float* __restrict__ partsum,
    const float* __restrict__ partmax, const float* __restrict__ diagv,
    float* __restrict__ accum) {
  __shared__ float sm[4];
  const int row = blockIdx.x*256 + threadIdx.x;
  float s = 0.f, mx = -1e30f;
  for (int i = 0; i < 64; i++) {
    s  += partsum[(size_t)i*BSZ + row];
    mx  = fmaxf(mx, partmax[(size_t)i*BSZ + row]);
  }
  const float dgs  = diagv[row];                 // scaled S_ii (participated in mx -> exact eq when max)
  const float corr = (dgs >= mx) ? 1.f : 0.f;
  const float lse  = logf(s);                    // ln(sum_j 2^(S_ij*log2e)) = ln(sum exp(S_ij))
  const float dg   = dgs * LN2;                  // unscale for loss
  const float lse_s = blk_sum256(lse, sm);
  const float dg_s  = blk_sum256(dg, sm);
  const float c_s   = blk_sum256(corr, sm);
  if (threadIdx.x == 0) {
    atomicAdd(&accum[0], lse_s);
    atomicAdd(&accum[1], dg_s);
    atomicAdd(&accum[2], c_s);
  }
}

__global__ void finalize_kernel(const float* __restrict__ accum, float* __restrict__ out) {
  out[0] = accum[0] - accum[1];
  out[1] = accum[2] * (1.f / BSZ);
}

// ---------------- launch ----------------
extern "C" void kernel_launch(void* const* d_in, const int* in_sizes, int n_in,
                              void* d_out, int out_size, void* d_ws, size_t ws_size,
                              hipStream_t stream) {
  const float* inp  = (const float*)d_in[0];
  const float* y    = (const float*)d_in[1];
  const float* ln1g = (const float*)d_in[2];
  const float* ln1b = (const float*)d_in[3];
  const float* W1   = (const float*)d_in[4];
  const float* b1   = (const float*)d_in[5];
  const float* Wa   = (const float*)d_in[6];
  const float* ba   = (const float*)d_in[7];
  const float* Wb   = (const float*)d_in[8];
  const float* bb   = (const float*)d_in[9];
  const float* W2   = (const float*)d_in[10];
  const float* b2   = (const float*)d_in[11];
  const float* ln2g = (const float*)d_in[12];
  const float* ln2b = (const float*)d_in[13];
  float* out = (float*)d_out;

  char* ws = (char*)d_ws;
  f16*   XH   = (f16*)  (ws + OFF_XH);
  f16*   PN   = (f16*)  (ws + OFF_PN);
  f16*   YN   = (f16*)  (ws + OFF_YN);
  float* PSUM = (float*)(ws + OFF_PSUM);
  float* PMAX = (float*)(ws + OFF_PMAX);
  f16*   HB   = (f16*)  (ws + OFF_HB);
  f16*   T    = (f16*)  (ws + OFF_TT);
  float* PRE2 = (float*)(ws + OFF_TT);
  float* H    = (float*)(ws + OFF_H);
  f16*   W1T  = (f16*)  (ws + OFF_W1T);
  f16*   WAT  = (f16*)  (ws + OFF_WAT);
  f16*   WBT  = (f16*)  (ws + OFF_WBT);
  f16*   W2T  = (f16*)  (ws + OFF_W2T);
  float* DIAG = (float*)(ws + OFF_DIAG);
  float* ACC  = (float*)(ws + OFF_ACC);

  transpose_cast<<<dim3(HID/32,  INP/32), 256, 0, stream>>>(W1, W1T, INP, HID);
  transpose_cast<<<dim3(HID/32,  HID/32), 256, 0, stream>>>(Wa, WAT, HID, HID);
  transpose_cast<<<dim3(HID/32,  HID/32), 256, 0, stream>>>(Wb, WBT, HID, HID);
  transpose_cast<<<dim3(OUTD/32, HID/32), 256, 0, stream>>>(W2, W2T, HID, OUTD);

  ln1_kernel<<<BSZ, 256, 0, stream>>>(inp, ln1g, ln1b, XH);

  gemm_bt<EPI_H><<<dim3(BSZ/128, HID/128), 256, 0, stream>>>(
      XH, W1T, INP, HID, b1, H, HB, nullptr, nullptr, nullptr, nullptr);

  for (int it = 0; it < 2; it++) {
    gemm_bt<EPI_T><<<dim3(BSZ/128, HID/128), 256, 0, stream>>>(
        HB, WAT, HID, HID, ba, nullptr, T, nullptr, nullptr, nullptr, nullptr);
    gemm_bt<EPI_RES><<<dim3(BSZ/128, HID/128), 256, 0, stream>>>(
        T, WBT, HID, HID, bb, H, HB, H, nullptr, nullptr, nullptr);
  }

  gemm_bt<EPI_P><<<dim3(BSZ/128, OUTD/128), 256, 0, stream>>>(
      HB, W2T, HID, OUTD, b2, PRE2, nullptr, nullptr, nullptr, nullptr, nullptr);

  ln2_kernel<<<BSZ, 256, 0, stream>>>(PRE2, ln2g, ln2b, out, PN);
  yn_kernel<<<BSZ, 256, 0, stream>>>(y, YN);

  hipMemsetAsync(ACC, 0, 4*sizeof(float), stream);

  gemm_bt<EPI_S><<<dim3(BSZ/128, BSZ/128), 256, 0, stream>>>(
      PN, YN, OUTD, BSZ, nullptr, nullptr, nullptr, nullptr, PSUM, PMAX, DIAG);

  reduce_rows<<<BSZ/256, 256, 0, stream>>>(PSUM, PMAX, DIAG, ACC);
  finalize_kernel<<<1, 1, 0, stream>>>(ACC, out + (size_t)BSZ*OUTD);
}

// Round 3
// 497.016 us; speedup vs baseline: 1.3503x; 1.1844x over previous
//
#include <hip/hip_runtime.h>
#include <hip/hip_fp16.h>
#include <cstdint>
#include <math.h>

#define INP  3072
#define HID  1024
#define OUTD 768
#define BSZ  8192

typedef _Float16 f16;
typedef _Float16 f16x8 __attribute__((ext_vector_type(8)));
typedef _Float16 f16x4 __attribute__((ext_vector_type(4)));
typedef float    f32x4 __attribute__((ext_vector_type(4)));
typedef int      i32x4 __attribute__((ext_vector_type(4)));
typedef signed char s8;

static constexpr float LOG2E = 1.44269504088896340736f;
static constexpr float LN2   = 0.69314718055994530942f;
static constexpr float QS    = 384.0f;             // i8 quant scale (|pn|,|yn| <= ~0.17 << 127/384)
static constexpr float CSC   = LOG2E / (QS * QS);  // i32 dot -> S * log2(e)

// ---------------- workspace layout (bytes) ----------------
// XH (f16, 50.3MB @0) is dead after GEMM1; region reused for PN/YN/partials.
static constexpr size_t OFF_XH   = 0;
static constexpr size_t OFF_PN   = 0;                                  // i8 8192x768
static constexpr size_t OFF_YN   = OFF_PN   + (size_t)BSZ*OUTD;        // i8
static constexpr size_t OFF_PSUM = OFF_YN   + (size_t)BSZ*OUTD;
static constexpr size_t OFF_PMAX = OFF_PSUM + (size_t)BSZ*64*4;        // ends ~16.8MB
static constexpr size_t OFF_HB   = OFF_XH   + (size_t)BSZ*INP*2;       // 50331648, f16 residual stream
static constexpr size_t OFF_TT   = OFF_HB   + (size_t)BSZ*HID*2;       // T f16 / PRE2 f32 share
static constexpr size_t OFF_W1T  = OFF_TT   + (size_t)BSZ*OUTD*4;
static constexpr size_t OFF_WAT  = OFF_W1T  + (size_t)INP*HID*2;
static constexpr size_t OFF_WBT  = OFF_WAT  + (size_t)HID*HID*2;
static constexpr size_t OFF_W2T  = OFF_WBT  + (size_t)HID*HID*2;
static constexpr size_t OFF_DIAG = OFF_W2T  + (size_t)HID*OUTD*2;
static constexpr size_t OFF_ACC  = OFF_DIAG + (size_t)BSZ*4;           // 3 sums + counter

#define GL2LDS(gp, lp) __builtin_amdgcn_global_load_lds( \
    (__attribute__((address_space(1))) void*)(uintptr_t)(gp), \
    (__attribute__((address_space(3))) void*)(unsigned)(uintptr_t)(lp), 16, 0, 0)

__device__ __forceinline__ float blk_sum256(float v, float* sm) {
  #pragma unroll
  for (int d = 1; d < 64; d <<= 1) v += __shfl_xor(v, d, 64);
  int tid = threadIdx.x;
  __syncthreads();
  if ((tid & 63) == 0) sm[tid >> 6] = v;
  __syncthreads();
  return sm[0] + sm[1] + sm[2] + sm[3];
}

__device__ __forceinline__ s8 q8(float v) {
  int q = __float2int_rn(v * QS);
  q = q > 127 ? 127 : (q < -127 ? -127 : q);
  return (s8)q;
}

// ---------------- LN1 (float4) ----------------
__global__ __launch_bounds__(256) void ln1_kernel(const float* __restrict__ inp,
    const float* __restrict__ g, const float* __restrict__ b, f16* __restrict__ xh) {
  __shared__ float sm[4];
  const int row = blockIdx.x, tid = threadIdx.x;
  const float4* x4 = (const float4*)(inp + (size_t)row * INP);
  float4 v[3]; float s = 0.f;
  #pragma unroll
  for (int i = 0; i < 3; i++) { v[i] = x4[tid + i*256]; s += v[i].x+v[i].y+v[i].z+v[i].w; }
  const float mean = blk_sum256(s, sm) * (1.f/INP);
  float s2 = 0.f;
  #pragma unroll
  for (int i = 0; i < 3; i++) {
    float dx=v[i].x-mean, dy=v[i].y-mean, dz=v[i].z-mean, dw=v[i].w-mean;
    s2 += dx*dx+dy*dy+dz*dz+dw*dw;
  }
  const float rstd = rsqrtf(blk_sum256(s2, sm) * (1.f/INP) + 1e-5f);
  const float4* g4p = (const float4*)g;
  const float4* b4p = (const float4*)b;
  f16x4* o4 = (f16x4*)(xh + (size_t)row * INP);
  #pragma unroll
  for (int i = 0; i < 3; i++) {
    const int c = tid + i*256;
    const float4 gg = g4p[c], bb = b4p[c];
    f16x4 t;
    t[0] = (f16)((v[i].x-mean)*rstd*gg.x + bb.x);
    t[1] = (f16)((v[i].y-mean)*rstd*gg.y + bb.y);
    t[2] = (f16)((v[i].z-mean)*rstd*gg.z + bb.z);
    t[3] = (f16)((v[i].w-mean)*rstd*gg.w + bb.w);
    o4[c] = t;
  }
}

// ---------------- all 4 weight transposes in one launch ----------------
__global__ __launch_bounds__(256) void transpose_all(
    const float* __restrict__ W1, const float* __restrict__ Wa,
    const float* __restrict__ Wb, const float* __restrict__ W2,
    f16* __restrict__ W1T, f16* __restrict__ WAT,
    f16* __restrict__ WBT, f16* __restrict__ W2T) {
  __shared__ float t[32][33];
  const int bI = blockIdx.x;
  const float* W; f16* Wt; int K, N, n0, k0;
  if (bI < 3072)      { int tt = bI;      W = W1; Wt = W1T; K = INP; N = HID;  n0 = (tt & 31)*32; k0 = (tt >> 5)*32; }
  else if (bI < 4096) { int tt = bI-3072; W = Wa; Wt = WAT; K = HID; N = HID;  n0 = (tt & 31)*32; k0 = (tt >> 5)*32; }
  else if (bI < 5120) { int tt = bI-4096; W = Wb; Wt = WBT; K = HID; N = HID;  n0 = (tt & 31)*32; k0 = (tt >> 5)*32; }
  else                { int tt = bI-5120; W = W2; Wt = W2T; K = HID; N = OUTD; int kq = tt/24; n0 = (tt - kq*24)*32; k0 = kq*32; }
  const int tx = threadIdx.x & 31, ty = threadIdx.x >> 5;
  #pragma unroll
  for (int i = 0; i < 32; i += 8) t[ty+i][tx] = W[(size_t)(k0+ty+i)*N + n0+tx];
  __syncthreads();
  #pragma unroll
  for (int i = 0; i < 32; i += 8) Wt[(size_t)(n0+ty+i)*K + k0+tx] = (f16)t[tx][ty+i];
}

// ---------------- LN2+normalize+quantize (rows 0..8191) & yn quantize (8192..) ----------------
__global__ __launch_bounds__(256) void ln2_yn(const float* __restrict__ pre,
    const float* __restrict__ g, const float* __restrict__ b,
    const float* __restrict__ y,
    float* __restrict__ outY, s8* __restrict__ pn, s8* __restrict__ yn) {
  __shared__ float sm[4];
  const int tid = threadIdx.x;
  if ((int)blockIdx.x < BSZ) {
    const int row = blockIdx.x;
    const float* x = pre + (size_t)row * OUTD;
    float v[3]; float s = 0.f;
    #pragma unroll
    for (int i = 0; i < 3; i++) { v[i] = x[tid + i*256]; s += v[i]; }
    const float mean = blk_sum256(s, sm) * (1.f/OUTD);
    float s2 = 0.f;
    #pragma unroll
    for (int i = 0; i < 3; i++) { float d = v[i]-mean; s2 += d*d; }
    const float rstd = rsqrtf(blk_sum256(s2, sm) * (1.f/OUTD) + 1e-5f);
    float z[3]; float n2 = 0.f;
    #pragma unroll
    for (int i = 0; i < 3; i++) { int c = tid + i*256; z[i] = (v[i]-mean)*rstd*g[c] + b[c]; n2 += z[i]*z[i]; }
    const float rn = rsqrtf(blk_sum256(n2, sm));
    float* oy = outY + (size_t)row * OUTD;
    s8*   op = pn   + (size_t)row * OUTD;
    #pragma unroll
    for (int i = 0; i < 3; i++) { int c = tid + i*256; oy[c] = z[i]; op[c] = q8(z[i]*rn); }
  } else {
    const int row = blockIdx.x - BSZ;
    const float* x = y + (size_t)row * OUTD;
    float v[3]; float n2 = 0.f;
    #pragma unroll
    for (int i = 0; i < 3; i++) { v[i] = x[tid + i*256]; n2 += v[i]*v[i]; }
    const float rn = rsqrtf(blk_sum256(n2, sm));
    s8* o = yn + (size_t)row * OUTD;
    #pragma unroll
    for (int i = 0; i < 3; i++) { int c = tid + i*256; o[c] = q8(v[i]*rn); }
  }
}

// ---------------- f16 GEMM (backbone), XOR-swizzled LDS, dbuf ----------------
#define EPI_H   0
#define EPI_T   1
#define EPI_RES 2
#define EPI_P   3

template<int EPI>
__global__ __launch_bounds__(256) void gemm_bt(
    const f16* __restrict__ A, const f16* __restrict__ B, int K, int N,
    const float* __restrict__ bias, float* __restrict__ Cf, f16* __restrict__ Ch,
    const f16* __restrict__ Hin)
{
  __shared__ alignas(16) f16 lA[2][128*32];
  __shared__ alignas(16) f16 lB[2][128*32];
  const int tid  = threadIdx.x;
  const int wave = tid >> 6, lane = tid & 63;
  const int m0 = blockIdx.x * 128, n0 = blockIdx.y * 128;
  const int srow  = tid >> 2;
  const int skc   = tid & 3;
  const int skc_sw = skc ^ ((srow >> 1) & 3);
  const f16* gA = A + (size_t)(m0 + srow) * K + skc_sw*8;
  const f16* gB = B + (size_t)(n0 + srow) * K + skc_sw*8;
  const int wm = wave & 1, wn = wave >> 1;
  const int fm = lane & 15;
  const int g4 = lane >> 4;
  const int ks = (fm >> 1) & 3;
  const int ck = ((g4 ^ ks) * 8);

  f32x4 acc[4][4];
  #pragma unroll
  for (int i = 0; i < 4; i++)
    #pragma unroll
    for (int j = 0; j < 4; j++) acc[i][j] = (f32x4){0.f,0.f,0.f,0.f};

  const int iters = K >> 5;
  auto stage = [&](int buf, int k0) {
    f16* lAw = &lA[buf][wave*16*32];
    f16* lBw = &lB[buf][wave*16*32];
    GL2LDS(gA + k0,                lAw);
    GL2LDS(gA + (size_t)64*K + k0, lAw + 64*32);
    GL2LDS(gB + k0,                lBw);
    GL2LDS(gB + (size_t)64*K + k0, lBw + 64*32);
  };

  stage(0, 0);
  __syncthreads();
  for (int it = 0; it < iters; ++it) {
    const int cur = it & 1;
    if (it + 1 < iters) stage(cur ^ 1, (it + 1) << 5);
    f16x8 af[4], bf[4];
    #pragma unroll
    for (int i = 0; i < 4; i++) af[i] = *(const f16x8*)&lA[cur][(wm*64 + i*16 + fm)*32 + ck];
    #pragma unroll
    for (int j = 0; j < 4; j++) bf[j] = *(const f16x8*)&lB[cur][(wn*64 + j*16 + fm)*32 + ck];
    #pragma unroll
    for (int i = 0; i < 4; i++)
      #pragma unroll
      for (int j = 0; j < 4; j++)
        acc[i][j] = __builtin_amdgcn_mfma_f32_16x16x32_f16(af[i], bf[j], acc[i][j], 0, 0, 0);
    __syncthreads();
  }

  // C/D layout: col = lane&15, row = (lane>>4)*4 + reg
  const int colb = n0 + wn*64;
  const int rowb = m0 + wm*64;
  #pragma unroll
  for (int i = 0; i < 4; i++) {
    #pragma unroll
    for (int j = 0; j < 4; j++) {
      const int col = colb + j*16 + fm;
      const float bs = bias[col];
      #pragma unroll
      for (int r = 0; r < 4; r++) {
        const int row = rowb + i*16 + g4*4 + r;
        float v = acc[i][j][r] + bs;
        const size_t idx = (size_t)row * N + col;
        if constexpr (EPI == EPI_H)        { Ch[idx] = (f16)v; }
        else if constexpr (EPI == EPI_T)   { v = fmaxf(v, 0.f); Ch[idx] = (f16)v; }
        else if constexpr (EPI == EPI_RES) { v = fmaxf(v, 0.f); v += (float)Hin[idx]; Ch[idx] = (f16)v; }
        else                               { Cf[idx] = v; }
      }
    }
  }
}

// ---------------- int8 S-GEMM: S = pn.yn^T fused exp2-sum/max/diag ----------------
// A,B: [8192][768] i8 K-contiguous. BK=64 (one MFMA K per iter). 12 iters.
__global__ __launch_bounds__(256) void gemm_s8(
    const s8* __restrict__ A, const s8* __restrict__ B,
    float* __restrict__ partsum, float* __restrict__ partmax, float* __restrict__ diagv)
{
  __shared__ alignas(16) s8 lA[2][128*64];
  __shared__ alignas(16) s8 lB[2][128*64];
  __shared__ float redS[2][128], redM[2][128];
  const int K = OUTD;
  const int tid = threadIdx.x;
  const int wave = tid >> 6, lane = tid & 63;
  const int m0 = blockIdx.x * 128, n0 = blockIdx.y * 128;
  // staging: 4 lanes/row, 16B chunks; XOR swizzle chunk ^ ((r ^ r>>2)&3) (2-way max)
  const int srow = tid >> 2;
  const int cl   = tid & 3;
  const int cg   = cl ^ ((srow ^ (srow >> 2)) & 3);
  const s8* gA = A + (size_t)(m0 + srow) * K + cg*16;
  const s8* gB = B + (size_t)(n0 + srow) * K + cg*16;
  const int wm = wave & 1, wn = wave >> 1;
  const int fm = lane & 15;
  const int g4 = lane >> 4;
  const int ksw = (fm ^ (fm >> 2)) & 3;
  const int ck8 = (g4 ^ ksw) * 16;      // byte offset of k-chunk within 64B row

  i32x4 acc[4][4];
  #pragma unroll
  for (int i = 0; i < 4; i++)
    #pragma unroll
    for (int j = 0; j < 4; j++) acc[i][j] = (i32x4){0,0,0,0};

  auto stage = [&](int buf, int k0) {
    s8* lAw = &lA[buf][wave*16*64];
    s8* lBw = &lB[buf][wave*16*64];
    GL2LDS(gA + k0,                lAw);
    GL2LDS(gA + (size_t)64*K + k0, lAw + 64*64);
    GL2LDS(gB + k0,                lBw);
    GL2LDS(gB + (size_t)64*K + k0, lBw + 64*64);
  };

  stage(0, 0);
  __syncthreads();
  const int iters = K / 64;   // 12
  for (int it = 0; it < iters; ++it) {
    const int cur = it & 1;
    if (it + 1 < iters) stage(cur ^ 1, (it + 1) * 64);
    i32x4 af[4], bf[4];
    #pragma unroll
    for (int i = 0; i < 4; i++) af[i] = *(const i32x4*)&lA[cur][(wm*64 + i*16 + fm)*64 + ck8];
    #pragma unroll
    for (int j = 0; j < 4; j++) bf[j] = *(const i32x4*)&lB[cur][(wn*64 + j*16 + fm)*64 + ck8];
    #pragma unroll
    for (int i = 0; i < 4; i++)
      #pragma unroll
      for (int j = 0; j < 4; j++)
        acc[i][j] = __builtin_amdgcn_mfma_i32_16x16x64_i8(af[i], bf[j], acc[i][j], 0, 0, 0);
    __syncthreads();
  }

  // epilogue: values scaled to S*log2e via CSC
  if (m0 == n0) {
    #pragma unroll
    for (int i = 0; i < 4; i++)
      #pragma unroll
      for (int j = 0; j < 4; j++) {
        const int col = n0 + wn*64 + j*16 + fm;
        #pragma unroll
        for (int r = 0; r < 4; r++) {
          const int row = m0 + wm*64 + i*16 + g4*4 + r;
          if (row == col) diagv[row] = (float)acc[i][j][r] * CSC;
        }
      }
  }
  #pragma unroll
  for (int i = 0; i < 4; i++) {
    #pragma unroll
    for (int r = 0; r < 4; r++) {
      const float a0 = (float)acc[i][0][r] * CSC;
      const float a1 = (float)acc[i][1][r] * CSC;
      const float a2 = (float)acc[i][2][r] * CSC;
      const float a3 = (float)acc[i][3][r] * CSC;
      float s  = exp2f(a0) + exp2f(a1) + exp2f(a2) + exp2f(a3);
      float mx = fmaxf(fmaxf(a0, a1), fmaxf(a2, a3));
      #pragma unroll
      for (int d = 1; d < 16; d <<= 1) {
        s  += __shfl_xor(s, d, 64);
        mx  = fmaxf(mx, __shfl_xor(mx, d, 64));
      }
      if (fm == 0) { const int lrow = wm*64 + i*16 + g4*4 + r; redS[wn][lrow] = s; redM[wn][lrow] = mx; }
    }
  }
  __syncthreads();
  if (tid < 128) {
    const float sa = redS[0][tid] + redS[1][tid];
    const float ma = fmaxf(redM[0][tid], redM[1][tid]);
    const size_t p = (size_t)blockIdx.y * BSZ + m0 + tid;
    partsum[p] = sa; partmax[p] = ma;
  }
}

// ---------------- final reduce (+ inlined finalize via atomic counter) ----------------
__global__ __launch_bounds__(256) void reduce_rows(const float* __restrict__ partsum,
    const float* __restrict__ partmax, const float* __restrict__ diagv,
    float* __restrict__ accum, float* __restrict__ out) {
  __shared__ float sm[4];
  const int row = blockIdx.x*256 + threadIdx.x;
  float s = 0.f, mx = -1e30f;
  for (int i = 0; i < 64; i++) {
    s  += partsum[(size_t)i*BSZ + row];
    mx  = fmaxf(mx, partmax[(size_t)i*BSZ + row]);
  }
  const float dgs  = diagv[row];             // scaled S_ii*log2e; participated in mx -> exact eq test
  const float corr = (dgs >= mx) ? 1.f : 0.f;
  const float lse  = logf(s);                // ln(sum 2^(S*log2e)) = ln(sum exp(S))
  const float dg   = dgs * LN2;
  const float lse_s = blk_sum256(lse, sm);
  const float dg_s  = blk_sum256(dg, sm);
  const float c_s   = blk_sum256(corr, sm);
  if (threadIdx.x == 0) {
    atomicAdd(&accum[0], lse_s);
    atomicAdd(&accum[1], dg_s);
    atomicAdd(&accum[2], c_s);
    __threadfence();
    const unsigned old = atomicAdd((unsigned*)&accum[3], 1u);
    if (old == gridDim.x - 1) {
      const float a0 = atomicAdd(&accum[0], 0.f);  // device-scope RMW read (XCD-safe)
      const float a1 = atomicAdd(&accum[1], 0.f);
      const float a2 = atomicAdd(&accum[2], 0.f);
      out[0] = a0 - a1;
      out[1] = a2 * (1.f / BSZ);
    }
  }
}

// ---------------- launch ----------------
extern "C" void kernel_launch(void* const* d_in, const int* in_sizes, int n_in,
                              void* d_out, int out_size, void* d_ws, size_t ws_size,
                              hipStream_t stream) {
  const float* inp  = (const float*)d_in[0];
  const float* y    = (const float*)d_in[1];
  const float* ln1g = (const float*)d_in[2];
  const float* ln1b = (const float*)d_in[3];
  const float* W1   = (const float*)d_in[4];
  const float* b1   = (const float*)d_in[5];
  const float* Wa   = (const float*)d_in[6];
  const float* ba   = (const float*)d_in[7];
  const float* Wb   = (const float*)d_in[8];
  const float* bb   = (const float*)d_in[9];
  const float* W2   = (const float*)d_in[10];
  const float* b2   = (const float*)d_in[11];
  const float* ln2g = (const float*)d_in[12];
  const float* ln2b = (const float*)d_in[13];
  float* out = (float*)d_out;

  char* ws = (char*)d_ws;
  f16*   XH   = (f16*)  (ws + OFF_XH);
  s8*    PN   = (s8*)   (ws + OFF_PN);
  s8*    YN   = (s8*)   (ws + OFF_YN);
  float* PSUM = (float*)(ws + OFF_PSUM);
  float* PMAX = (float*)(ws + OFF_PMAX);
  f16*   HB   = (f16*)  (ws + OFF_HB);
  f16*   T    = (f16*)  (ws + OFF_TT);
  float* PRE2 = (float*)(ws + OFF_TT);
  f16*   W1T  = (f16*)  (ws + OFF_W1T);
  f16*   WAT  = (f16*)  (ws + OFF_WAT);
  f16*   WBT  = (f16*)  (ws + OFF_WBT);
  f16*   W2T  = (f16*)  (ws + OFF_W2T);
  float* DIAG = (float*)(ws + OFF_DIAG);
  float* ACC  = (float*)(ws + OFF_ACC);

  transpose_all<<<5888, 256, 0, stream>>>(W1, Wa, Wb, W2, W1T, WAT, WBT, W2T);
  ln1_kernel<<<BSZ, 256, 0, stream>>>(inp, ln1g, ln1b, XH);

  gemm_bt<EPI_H><<<dim3(BSZ/128, HID/128), 256, 0, stream>>>(
      XH, W1T, INP, HID, b1, nullptr, HB, nullptr);

  for (int it = 0; it < 2; it++) {
    gemm_bt<EPI_T><<<dim3(BSZ/128, HID/128), 256, 0, stream>>>(
        HB, WAT, HID, HID, ba, nullptr, T, nullptr);
    gemm_bt<EPI_RES><<<dim3(BSZ/128, HID/128), 256, 0, stream>>>(
        T, WBT, HID, HID, bb, nullptr, HB, HB);
  }

  gemm_bt<EPI_P><<<dim3(BSZ/128, OUTD/128), 256, 0, stream>>>(
      HB, W2T, HID, OUTD, b2, PRE2, nullptr, nullptr);

  ln2_yn<<<2*BSZ, 256, 0, stream>>>(PRE2, ln2g, ln2b, y, out, PN, YN);

  hipMemsetAsync(ACC, 0, 4*sizeof(float), stream);

  gemm_s8<<<dim3(BSZ/128, BSZ/128), 256, 0, stream>>>(PN, YN, PSUM, PMAX, DIAG);

  reduce_rows<<<BSZ/256, 256, 0, stream>>>(PSUM, PMAX, DIAG, ACC, out + (size_t)BSZ*OUTD);
}